// Round 2
// baseline (419.101 us; speedup 1.0000x reference)
//
#include <hip/hip_runtime.h>
#include <hip/hip_bf16.h>
#include <math.h>

// ---------------------------------------------------------------------------
// GCN forward: out = log_softmax( A@( relu(A@(x@W1)+b1) @ W2 ) + b2 )
// Round 6: spmm1 - scalarized col/val (readfirstlane -> SALU addressing) and
// a 2-bank software pipeline with an asm data-fence on gather results, so the
// compiler emits counted vmcnt waits (8 loads stay in flight during FMAs)
// instead of interleaving issue/consume at VGPR=32.
// spmm2 - sup2 rows padded to 128 B (32 uints) so each 20-lane gather hits
// exactly one L2 line; gather fence added.
// ---------------------------------------------------------------------------

#define GCN_NFEAT 256
#define GCN_NHID  128
#define GCN_NCLASS 40
#define SUP2_LD   64          // padded row length (bf16 elems) = 128 B

typedef __bf16 bf16_t;
typedef bf16_t bf16x8 __attribute__((ext_vector_type(8)));
typedef float  f32x4  __attribute__((ext_vector_type(4)));

static __device__ __forceinline__ unsigned short f2b(float f) {
    bf16_t b = (bf16_t)f;
    return *(unsigned short*)&b;
}
static __device__ __forceinline__ float blo(unsigned int u) {
    return __uint_as_float(u << 16);
}
static __device__ __forceinline__ float bhi(unsigned int u) {
    return __uint_as_float(u & 0xffff0000u);
}

// ---- row_ptr[r] = lower_bound(adj_row, r), r in [0, N] ---------------------
__global__ __launch_bounds__(256) void k_row_ptr(
    const int* __restrict__ row, int* __restrict__ row_ptr, int n_rows, int n_edges)
{
    int r = blockIdx.x * blockDim.x + threadIdx.x;
    if (r > n_rows) return;
    int lo = 0, hi = n_edges;
    while (lo < hi) {
        int mid = (lo + hi) >> 1;
        if (row[mid] < r) lo = mid + 1; else hi = mid;
    }
    row_ptr[r] = lo;
}

// ---- prep: W1t_bf16[128][256] = bf16(W1[k][c]) transposed ------------------
__global__ __launch_bounds__(256) void k_prep_w1t(
    const float* __restrict__ w1, bf16_t* __restrict__ w1t)
{
    int idx = blockIdx.x * 256 + threadIdx.x;           // 128*256 total
    int c = idx & 127;
    int k = idx >> 7;
    w1t[(size_t)c * GCN_NFEAT + k] = (bf16_t)w1[(size_t)k * GCN_NHID + c];
}

// ---- prep: W2t_bf16[48][128], cols 40..47 zero -----------------------------
__global__ __launch_bounds__(256) void k_prep_w2t(
    const float* __restrict__ w2, bf16_t* __restrict__ w2t)
{
    int idx = blockIdx.x * 256 + threadIdx.x;           // 48*128 = 6144 total
    if (idx >= 48 * GCN_NHID) return;
    int c = idx / GCN_NHID;
    int k = idx - c * GCN_NHID;
    float v = (c < GCN_NCLASS) ? w2[(size_t)k * GCN_NCLASS + c] : 0.f;
    w2t[idx] = (bf16_t)v;
}

// ---- GEMM1 (MFMA): sup1_bf16[N,128] = bf16( x[N,256] @ W1 ) ----------------
__global__ __launch_bounds__(256) void k_gemm1(
    const float* __restrict__ x, const bf16_t* __restrict__ w1t,
    bf16_t* __restrict__ out, int nrows)
{
    __shared__ __align__(16) bf16_t As[128][72];   // [row][k]
    __shared__ __align__(16) bf16_t Bs[128][72];   // [col][k]

    const int tid  = threadIdx.x;
    const int wave = tid >> 6, lane = tid & 63;
    const int wm = wave >> 1, wn = wave & 1;
    const int lm = lane & 15, quad = lane >> 4;
    const int r0 = blockIdx.x * 128;

    f32x4 acc[4][4] = {};

    for (int k0 = 0; k0 < GCN_NFEAT; k0 += 64) {
        {
            const int row = tid >> 1, half = tid & 1;
            const int gr = r0 + row;
            union { bf16_t b[32]; uint4 q[4]; } t;
            if (gr < nrows) {
                const float* p = x + (size_t)gr * GCN_NFEAT + k0 + half * 32;
#pragma unroll
                for (int i = 0; i < 8; i++) {
                    float4 v = ((const float4*)p)[i];
                    t.b[i*4+0] = (bf16_t)v.x; t.b[i*4+1] = (bf16_t)v.y;
                    t.b[i*4+2] = (bf16_t)v.z; t.b[i*4+3] = (bf16_t)v.w;
                }
            } else {
#pragma unroll
                for (int i = 0; i < 4; i++) t.q[i] = make_uint4(0,0,0,0);
            }
            uint4* dst = (uint4*)&As[row][half * 32];
#pragma unroll
            for (int i = 0; i < 4; i++) dst[i] = t.q[i];
        }
        {
            const int colc = tid >> 1, half = tid & 1;
            const uint4* src = (const uint4*)(w1t + (size_t)colc * GCN_NFEAT + k0 + half * 32);
            uint4* dst = (uint4*)&Bs[colc][half * 32];
#pragma unroll
            for (int i = 0; i < 4; i++) dst[i] = src[i];
        }
        __syncthreads();

#pragma unroll
        for (int ks = 0; ks < 2; ks++) {
            bf16x8 af[4], bfr[4];
#pragma unroll
            for (int i = 0; i < 4; i++)
                af[i] = *(const bf16x8*)&As[wm*64 + i*16 + lm][ks*32 + quad*8];
#pragma unroll
            for (int j = 0; j < 4; j++)
                bfr[j] = *(const bf16x8*)&Bs[wn*64 + j*16 + lm][ks*32 + quad*8];
#pragma unroll
            for (int i = 0; i < 4; i++)
#pragma unroll
                for (int j = 0; j < 4; j++)
                    acc[i][j] = __builtin_amdgcn_mfma_f32_16x16x32_bf16(
                        af[i], bfr[j], acc[i][j], 0, 0, 0);
        }
        __syncthreads();
    }

#pragma unroll
    for (int i = 0; i < 4; i++) {
#pragma unroll
        for (int reg = 0; reg < 4; reg++) {
            const int gr = r0 + wm*64 + i*16 + quad*4 + reg;
            if (gr < nrows) {
#pragma unroll
                for (int j = 0; j < 4; j++) {
                    const int gc = wn*64 + j*16 + lm;
                    out[(size_t)gr * GCN_NHID + gc] = (bf16_t)acc[i][j][reg];
                }
            }
        }
    }
}

// ---- spmm1: h_bf16[r,:] = relu( sum_e val[e]*sup1[col[e],:] + b1 ) ---------
// wave per row. col/val indices are wave-uniform (readfirstlane) -> scalar
// loads + SALU gather bases. 8-edge banks, 2-deep software pipeline; an asm
// data-fence on each bank's gather results stops the FMAs hoisting into the
// issue phase, so bank B's 8 gathers stay in flight during bank A's FMAs.
#define SPMM1_LOADCV(CS, VS, B)                                          \
    _Pragma("unroll")                                                    \
    for (int j = 0; j < 8; j++) {                                        \
        int gi = e0 + (B) + j;                                           \
        if (gi > emax) gi = emax;                                        \
        CS[j] = col[gi];                                                 \
        VS[j] = ((B) + j < n) ? val[gi] : 0.f;                           \
    }

#define SPMM1_ISSUE(U, CS)                                               \
    _Pragma("unroll")                                                    \
    for (int j = 0; j < 8; j++) {                                        \
        const unsigned int* p = sup + ((size_t)(unsigned)CS[j] << 6);    \
        U[j] = p[lane];                                                  \
    }

#define SPMM1_FENCE(U)                                                   \
    asm volatile("" : "+v"(U[0]), "+v"(U[1]), "+v"(U[2]), "+v"(U[3]),    \
                      "+v"(U[4]), "+v"(U[5]), "+v"(U[6]), "+v"(U[7]));

#define SPMM1_FMA(U, VS)                                                 \
    _Pragma("unroll")                                                    \
    for (int j = 0; j < 8; j++) {                                        \
        ax = fmaf(VS[j], blo(U[j]), ax);                                 \
        ay = fmaf(VS[j], bhi(U[j]), ay);                                 \
    }

__global__ __launch_bounds__(256) void k_spmm1(
    const int* __restrict__ row_ptr, const int* __restrict__ col,
    const float* __restrict__ val, const unsigned int* __restrict__ sup,
    const float* __restrict__ b1, unsigned int* __restrict__ h,
    int nrows, int n_edges)
{
    const int wid  = (blockIdx.x * blockDim.x + threadIdx.x) >> 6;
    const int lane = threadIdx.x & 63;
    if (wid >= nrows) return;
    const int e0   = __builtin_amdgcn_readfirstlane(row_ptr[wid]);
    const int e1   = __builtin_amdgcn_readfirstlane(row_ptr[wid + 1]);
    const int n    = e1 - e0;               // wave-uniform
    const int emax = n_edges - 1;

    float ax = 0.f, ay = 0.f;

    if (n > 0) {
        int   csA[8], csB[8];
        float vsA[8], vsB[8];
        unsigned uA[8], uB[8];

        SPMM1_LOADCV(csA, vsA, 0)
        SPMM1_ISSUE(uA, csA)
        int base = 0;
        while (true) {
            if (base + 8 < n) {
                SPMM1_LOADCV(csB, vsB, base + 8)
                SPMM1_ISSUE(uB, csB)
            }
            SPMM1_FENCE(uA)
            SPMM1_FMA(uA, vsA)
            base += 8;
            if (base >= n) break;
            if (base + 8 < n) {
                SPMM1_LOADCV(csA, vsA, base + 8)
                SPMM1_ISSUE(uA, csA)
            }
            SPMM1_FENCE(uB)
            SPMM1_FMA(uB, vsB)
            base += 8;
            if (base >= n) break;
        }
    }

    const float2 bb = *(const float2*)(b1 + lane * 2);
    const float ox = fmaxf(ax + bb.x, 0.f);
    const float oy = fmaxf(ay + bb.y, 0.f);
    h[(unsigned)(wid << 6) + lane] = (unsigned int)f2b(ox) | ((unsigned int)f2b(oy) << 16);
}

// ---- GEMM2 (MFMA): sup2_bf16[N,64(pad)] = bf16( h[N,128] @ W2 ) ------------
// output rows padded to 128 B so spmm2 gathers hit exactly one L2 line.
__global__ __launch_bounds__(256) void k_gemm2(
    const bf16_t* __restrict__ h, const bf16_t* __restrict__ w2t,
    bf16_t* __restrict__ out, int nrows)
{
    __shared__ __align__(16) bf16_t As[128][136];  // [row][k]
    __shared__ __align__(16) bf16_t Bs[48][136];   // [col][k]

    const int tid  = threadIdx.x;
    const int wave = tid >> 6, lane = tid & 63;
    const int lm = lane & 15, quad = lane >> 4;
    const int r0 = blockIdx.x * 128;

    {
        const int row = tid >> 1, half = tid & 1;
        const int gr = r0 + row;
        uint4* dst = (uint4*)&As[row][half * 64];
        if (gr < nrows) {
            const uint4* src = (const uint4*)(h + (size_t)gr * GCN_NHID + half * 64);
#pragma unroll
            for (int i = 0; i < 8; i++) dst[i] = src[i];
        } else {
#pragma unroll
            for (int i = 0; i < 8; i++) dst[i] = make_uint4(0,0,0,0);
        }
    }
    // stage B: 48 rows x 16 uint4 (full 256 B row)
    for (int idx = tid; idx < 48 * 16; idx += 256) {
        const int c = idx >> 4, seg = idx & 15;
        ((uint4*)&Bs[c][0])[seg] = ((const uint4*)(w2t + (size_t)c * GCN_NHID))[seg];
    }
    __syncthreads();

    f32x4 acc[2][3] = {};
#pragma unroll
    for (int ks = 0; ks < 4; ks++) {
        bf16x8 af[2], bfr[3];
#pragma unroll
        for (int i = 0; i < 2; i++)
            af[i] = *(const bf16x8*)&As[wave*32 + i*16 + lm][ks*32 + quad*8];
#pragma unroll
        for (int j = 0; j < 3; j++)
            bfr[j] = *(const bf16x8*)&Bs[j*16 + lm][ks*32 + quad*8];
#pragma unroll
        for (int i = 0; i < 2; i++)
#pragma unroll
            for (int j = 0; j < 3; j++)
                acc[i][j] = __builtin_amdgcn_mfma_f32_16x16x32_bf16(
                    af[i], bfr[j], acc[i][j], 0, 0, 0);
    }

#pragma unroll
    for (int i = 0; i < 2; i++) {
#pragma unroll
        for (int reg = 0; reg < 4; reg++) {
            const int gr = r0 + wave*32 + i*16 + quad*4 + reg;
            if (gr < nrows) {
#pragma unroll
                for (int j = 0; j < 3; j++) {
                    const int gc = j*16 + lm;          // 0..47, cols 40+ are pad
                    out[(size_t)gr * SUP2_LD + gc] = (bf16_t)acc[i][j][reg];
                }
            }
        }
    }
}

// ---- spmm2 + bias + log_softmax -> out[N,40] fp32 --------------------------
// 3 rows per wave: group g = lane/20 handles row wid*3+g, li = lane%20 owns
// classes {2li, 2li+1} packed in one uint. sup2 rows padded to 32 uints so a
// group's gather stays within one 128 B line. 8-edge unroll + gather fence.
__global__ __launch_bounds__(256) void k_spmm2_lsm(
    const int* __restrict__ row_ptr, const int* __restrict__ col,
    const float* __restrict__ val, const unsigned int* __restrict__ sup2,
    const float* __restrict__ b2, float* __restrict__ out, int nrows)
{
    const int wid  = (blockIdx.x * blockDim.x + threadIdx.x) >> 6;
    const int lane = threadIdx.x & 63;
    const int g    = lane / 20;            // 0..2 valid, 3 = idle lanes 60-63
    const int li   = lane - g * 20;
    const int r    = wid * 3 + g;
    const bool active = (g < 3) && (r < nrows);

    int e0 = 0, e1 = 0;
    if (active) { e0 = row_ptr[r]; e1 = row_ptr[r + 1]; }

    float ax = 0.f, ay = 0.f;
    int e = e0;
    for (; e + 7 < e1; e += 8) {
        const int c0 = col[e],   c1 = col[e+1], c2 = col[e+2], c3 = col[e+3];
        const int c4 = col[e+4], c5 = col[e+5], c6 = col[e+6], c7 = col[e+7];
        const float v0 = val[e],   v1 = val[e+1], v2 = val[e+2], v3 = val[e+3];
        const float v4 = val[e+4], v5 = val[e+5], v6 = val[e+6], v7 = val[e+7];
        unsigned int u0 = sup2[((unsigned)c0 << 5) + li];
        unsigned int u1 = sup2[((unsigned)c1 << 5) + li];
        unsigned int u2 = sup2[((unsigned)c2 << 5) + li];
        unsigned int u3 = sup2[((unsigned)c3 << 5) + li];
        unsigned int u4 = sup2[((unsigned)c4 << 5) + li];
        unsigned int u5 = sup2[((unsigned)c5 << 5) + li];
        unsigned int u6 = sup2[((unsigned)c6 << 5) + li];
        unsigned int u7 = sup2[((unsigned)c7 << 5) + li];
        asm volatile("" : "+v"(u0), "+v"(u1), "+v"(u2), "+v"(u3),
                          "+v"(u4), "+v"(u5), "+v"(u6), "+v"(u7));
        ax = fmaf(v0, blo(u0), ax); ay = fmaf(v0, bhi(u0), ay);
        ax = fmaf(v1, blo(u1), ax); ay = fmaf(v1, bhi(u1), ay);
        ax = fmaf(v2, blo(u2), ax); ay = fmaf(v2, bhi(u2), ay);
        ax = fmaf(v3, blo(u3), ax); ay = fmaf(v3, bhi(u3), ay);
        ax = fmaf(v4, blo(u4), ax); ay = fmaf(v4, bhi(u4), ay);
        ax = fmaf(v5, blo(u5), ax); ay = fmaf(v5, bhi(u5), ay);
        ax = fmaf(v6, blo(u6), ax); ay = fmaf(v6, bhi(u6), ay);
        ax = fmaf(v7, blo(u7), ax); ay = fmaf(v7, bhi(u7), ay);
    }
    for (; e + 3 < e1; e += 4) {
        const int c0 = col[e],   c1 = col[e+1], c2 = col[e+2], c3 = col[e+3];
        const float v0 = val[e], v1 = val[e+1], v2 = val[e+2], v3 = val[e+3];
        unsigned int u0 = sup2[((unsigned)c0 << 5) + li];
        unsigned int u1 = sup2[((unsigned)c1 << 5) + li];
        unsigned int u2 = sup2[((unsigned)c2 << 5) + li];
        unsigned int u3 = sup2[((unsigned)c3 << 5) + li];
        asm volatile("" : "+v"(u0), "+v"(u1), "+v"(u2), "+v"(u3));
        ax = fmaf(v0, blo(u0), ax); ay = fmaf(v0, bhi(u0), ay);
        ax = fmaf(v1, blo(u1), ax); ay = fmaf(v1, bhi(u1), ay);
        ax = fmaf(v2, blo(u2), ax); ay = fmaf(v2, bhi(u2), ay);
        ax = fmaf(v3, blo(u3), ax); ay = fmaf(v3, bhi(u3), ay);
    }
    for (; e < e1; e++) {
        const unsigned int u = sup2[((unsigned)col[e] << 5) + li];
        const float v = val[e];
        ax = fmaf(v, blo(u), ax); ay = fmaf(v, bhi(u), ay);
    }

    float l0 = -INFINITY, l1 = -INFINITY;
    if (active) {
        l0 = ax + b2[li * 2];
        l1 = ay + b2[li * 2 + 1];
    }

    // group-local (20-lane) shuffle reductions
    float m = fmaxf(l0, l1);
#pragma unroll
    for (int off = 16; off >= 1; off >>= 1) {
        const float t = __shfl_down(m, off, 64);
        if (li + off < 20) m = fmaxf(m, t);
    }
    m = __shfl(m, g * 20, 64);   // broadcast group max

    float s = active ? (__expf(l0 - m) + __expf(l1 - m)) : 0.f;
#pragma unroll
    for (int off = 16; off >= 1; off >>= 1) {
        const float t = __shfl_down(s, off, 64);
        if (li + off < 20) s += t;
    }
    s = __shfl(s, g * 20, 64);

    if (active) {
        const float lse = m + __logf(s);
        float* p = out + (size_t)r * GCN_NCLASS + li * 2;
        p[0] = l0 - lse;
        p[1] = l1 - lse;
    }
}

// ---------------------------------------------------------------------------
extern "C" void kernel_launch(void* const* d_in, const int* in_sizes, int n_in,
                              void* d_out, int out_size, void* d_ws, size_t ws_size,
                              hipStream_t stream)
{
    const float* x       = (const float*)d_in[0];
    const int*   adj_row = (const int*)  d_in[1];
    const int*   adj_col = (const int*)  d_in[2];
    const float* adj_val = (const float*)d_in[3];
    // d_in[4] = i (unused)
    const float* W1 = (const float*)d_in[5];
    const float* b1 = (const float*)d_in[6];
    const float* W2 = (const float*)d_in[7];
    const float* b2 = (const float*)d_in[8];
    float* out = (float*)d_out;

    const int N = in_sizes[0] / GCN_NFEAT;   // 100000
    const int E = in_sizes[1];               // 3200000

    // workspace layout (1 KiB aligned chunks)
    char* ws = (char*)d_ws;
    size_t off = 0;
    int* row_ptr = (int*)(ws + off);
    off += (((size_t)(N + 1) * sizeof(int)) + 1023) & ~(size_t)1023;
    bf16_t* w1t = (bf16_t*)(ws + off);                 // 128*256 bf16
    off += ((size_t)GCN_NHID * GCN_NFEAT * 2 + 1023) & ~(size_t)1023;
    bf16_t* w2t = (bf16_t*)(ws + off);                 // 48*128 bf16
    off += ((size_t)48 * GCN_NHID * 2 + 1023) & ~(size_t)1023;
    bf16_t* sup1 = (bf16_t*)(ws + off);                // N*128 bf16
    off += ((size_t)N * GCN_NHID * 2 + 1023) & ~(size_t)1023;
    bf16_t* h = (bf16_t*)(ws + off);                   // N*128 bf16
    bf16_t* sup2 = sup1;                               // reuse sup1 (N*64 bf16 padded)

    k_row_ptr<<<(N + 1 + 255) / 256, 256, 0, stream>>>(adj_row, row_ptr, N, E);
    k_prep_w1t<<<GCN_NHID * GCN_NFEAT / 256, 256, 0, stream>>>(W1, w1t);
    k_prep_w2t<<<(48 * GCN_NHID + 255) / 256, 256, 0, stream>>>(W2, w2t);
    k_gemm1<<<(N + 127) / 128, 256, 0, stream>>>(x, w1t, sup1, N);
    k_spmm1<<<(N + 3) / 4, 256, 0, stream>>>(row_ptr, adj_col, adj_val,
                                             (const unsigned int*)sup1, b1,
                                             (unsigned int*)h, N, E);
    k_gemm2<<<(N + 127) / 128, 256, 0, stream>>>(h, w2t, sup2, N);
    const int nw2 = (N + 2) / 3;                       // waves for spmm2
    k_spmm2_lsm<<<(nw2 + 3) / 4, 256, 0, stream>>>(row_ptr, adj_col, adj_val,
                                                   (const unsigned int*)sup2, b2, out, N);
}

// Round 3
// 392.904 us; speedup vs baseline: 1.0667x; 1.0667x over previous
//
#include <hip/hip_runtime.h>
#include <hip/hip_bf16.h>
#include <math.h>

// ---------------------------------------------------------------------------
// GCN forward: out = log_softmax( A@( relu(A@(x@W1)+b1) @ W2 ) + b2 )
// Round 7: quarter-gather spmm. One wave64 dwordx4 gather = 4 edges (each
// 16-lane quarter fetches one full 256 B sup1 row; lane f owns features
// 8f..8f+7). 4x fewer load/addr instrs per edge, 4x edges per vmcnt slot.
// col/val fetched per-lane as small broadcast vector loads (no s_load chain
// - R6 regression root cause). End of row: 2 shfl_xor rounds fold quarters.
// spmm2 same structure with dwordx2 on 128 B padded sup2 rows (1 line/edge),
// fused log_softmax, 1 row/wave. Tails = guarded static banks (no MLP=1 tail).
// ---------------------------------------------------------------------------

#define GCN_NFEAT 256
#define GCN_NHID  128
#define GCN_NCLASS 40
#define SUP2_LD   64          // padded row length (bf16 elems) = 128 B

typedef __bf16 bf16_t;
typedef bf16_t bf16x8 __attribute__((ext_vector_type(8)));
typedef float  f32x4  __attribute__((ext_vector_type(4)));

static __device__ __forceinline__ unsigned short f2b(float f) {
    bf16_t b = (bf16_t)f;
    return *(unsigned short*)&b;
}
static __device__ __forceinline__ float blo(unsigned int u) {
    return __uint_as_float(u << 16);
}
static __device__ __forceinline__ float bhi(unsigned int u) {
    return __uint_as_float(u & 0xffff0000u);
}

// ---- row_ptr[r] = lower_bound(adj_row, r), r in [0, N] ---------------------
__global__ __launch_bounds__(256) void k_row_ptr(
    const int* __restrict__ row, int* __restrict__ row_ptr, int n_rows, int n_edges)
{
    int r = blockIdx.x * blockDim.x + threadIdx.x;
    if (r > n_rows) return;
    int lo = 0, hi = n_edges;
    while (lo < hi) {
        int mid = (lo + hi) >> 1;
        if (row[mid] < r) lo = mid + 1; else hi = mid;
    }
    row_ptr[r] = lo;
}

// ---- prep: W1t_bf16[128][256] = bf16(W1[k][c]) transposed ------------------
__global__ __launch_bounds__(256) void k_prep_w1t(
    const float* __restrict__ w1, bf16_t* __restrict__ w1t)
{
    int idx = blockIdx.x * 256 + threadIdx.x;           // 128*256 total
    int c = idx & 127;
    int k = idx >> 7;
    w1t[(size_t)c * GCN_NFEAT + k] = (bf16_t)w1[(size_t)k * GCN_NHID + c];
}

// ---- prep: W2t_bf16[48][128], cols 40..47 zero -----------------------------
__global__ __launch_bounds__(256) void k_prep_w2t(
    const float* __restrict__ w2, bf16_t* __restrict__ w2t)
{
    int idx = blockIdx.x * 256 + threadIdx.x;           // 48*128 = 6144 total
    if (idx >= 48 * GCN_NHID) return;
    int c = idx / GCN_NHID;
    int k = idx - c * GCN_NHID;
    float v = (c < GCN_NCLASS) ? w2[(size_t)k * GCN_NCLASS + c] : 0.f;
    w2t[idx] = (bf16_t)v;
}

// ---- GEMM1 (MFMA): sup1_bf16[N,128] = bf16( x[N,256] @ W1 ) ----------------
__global__ __launch_bounds__(256) void k_gemm1(
    const float* __restrict__ x, const bf16_t* __restrict__ w1t,
    bf16_t* __restrict__ out, int nrows)
{
    __shared__ __align__(16) bf16_t As[128][72];   // [row][k]
    __shared__ __align__(16) bf16_t Bs[128][72];   // [col][k]

    const int tid  = threadIdx.x;
    const int wave = tid >> 6, lane = tid & 63;
    const int wm = wave >> 1, wn = wave & 1;
    const int lm = lane & 15, quad = lane >> 4;
    const int r0 = blockIdx.x * 128;

    f32x4 acc[4][4] = {};

    for (int k0 = 0; k0 < GCN_NFEAT; k0 += 64) {
        {
            const int row = tid >> 1, half = tid & 1;
            const int gr = r0 + row;
            union { bf16_t b[32]; uint4 q[4]; } t;
            if (gr < nrows) {
                const float* p = x + (size_t)gr * GCN_NFEAT + k0 + half * 32;
#pragma unroll
                for (int i = 0; i < 8; i++) {
                    float4 v = ((const float4*)p)[i];
                    t.b[i*4+0] = (bf16_t)v.x; t.b[i*4+1] = (bf16_t)v.y;
                    t.b[i*4+2] = (bf16_t)v.z; t.b[i*4+3] = (bf16_t)v.w;
                }
            } else {
#pragma unroll
                for (int i = 0; i < 4; i++) t.q[i] = make_uint4(0,0,0,0);
            }
            uint4* dst = (uint4*)&As[row][half * 32];
#pragma unroll
            for (int i = 0; i < 4; i++) dst[i] = t.q[i];
        }
        {
            const int colc = tid >> 1, half = tid & 1;
            const uint4* src = (const uint4*)(w1t + (size_t)colc * GCN_NFEAT + k0 + half * 32);
            uint4* dst = (uint4*)&Bs[colc][half * 32];
#pragma unroll
            for (int i = 0; i < 4; i++) dst[i] = src[i];
        }
        __syncthreads();

#pragma unroll
        for (int ks = 0; ks < 2; ks++) {
            bf16x8 af[4], bfr[4];
#pragma unroll
            for (int i = 0; i < 4; i++)
                af[i] = *(const bf16x8*)&As[wm*64 + i*16 + lm][ks*32 + quad*8];
#pragma unroll
            for (int j = 0; j < 4; j++)
                bfr[j] = *(const bf16x8*)&Bs[wn*64 + j*16 + lm][ks*32 + quad*8];
#pragma unroll
            for (int i = 0; i < 4; i++)
#pragma unroll
                for (int j = 0; j < 4; j++)
                    acc[i][j] = __builtin_amdgcn_mfma_f32_16x16x32_bf16(
                        af[i], bfr[j], acc[i][j], 0, 0, 0);
        }
        __syncthreads();
    }

#pragma unroll
    for (int i = 0; i < 4; i++) {
#pragma unroll
        for (int reg = 0; reg < 4; reg++) {
            const int gr = r0 + wm*64 + i*16 + quad*4 + reg;
            if (gr < nrows) {
#pragma unroll
                for (int j = 0; j < 4; j++) {
                    const int gc = wn*64 + j*16 + lm;
                    out[(size_t)gr * GCN_NHID + gc] = (bf16_t)acc[i][j][reg];
                }
            }
        }
    }
}

// ---- spmm1: h_bf16[r,:] = relu( sum_e val[e]*sup1[col[e],:] + b1 ) ---------
// wave per row, quarter-gather: quarter q = lane>>4 handles edge 4k+q of each
// group; lane f = lane&15 owns features 8f..8f+7 (one dwordx4 of the row).
#define S1_FENCE(U) asm volatile("" : "+v"(U.x), "+v"(U.y), "+v"(U.z), "+v"(U.w));
#define S1_FMA(U, V)                                   \
    a0 = fmaf(V, blo(U.x), a0); a1 = fmaf(V, bhi(U.x), a1); \
    a2 = fmaf(V, blo(U.y), a2); a3 = fmaf(V, bhi(U.y), a3); \
    a4 = fmaf(V, blo(U.z), a4); a5 = fmaf(V, bhi(U.z), a5); \
    a6 = fmaf(V, blo(U.w), a6); a7 = fmaf(V, bhi(U.w), a7);

__global__ __launch_bounds__(256) void k_spmm1(
    const int* __restrict__ row_ptr, const int* __restrict__ col,
    const float* __restrict__ val, const bf16_t* __restrict__ sup,
    const float* __restrict__ b1, unsigned int* __restrict__ h, int nrows)
{
    const int wid  = (blockIdx.x * blockDim.x + threadIdx.x) >> 6;
    const int lane = threadIdx.x & 63;
    if (wid >= nrows) return;
    const int q = lane >> 4;            // quarter: which edge of the group
    const int f = lane & 15;            // feature block 8f..8f+7
    const int e0 = __builtin_amdgcn_readfirstlane(row_ptr[wid]);
    const int e1 = __builtin_amdgcn_readfirstlane(row_ptr[wid + 1]);
    const int n  = e1 - e0;
    const char* supb = (const char*)sup;
    const int fo = f * 16;              // byte offset within row

    float a0=0.f,a1=0.f,a2=0.f,a3=0.f,a4=0.f,a5=0.f,a6=0.f,a7=0.f;

    int base = 0;
    // main: 16-edge chunks, 4 dwordx4 gathers in flight
    for (; base + 16 <= n; base += 16) {
        const int i0 = e0 + base + q;
        const int   c0 = col[i0];      const float v0 = val[i0];
        const int   c1 = col[i0 + 4];  const float v1 = val[i0 + 4];
        const int   c2 = col[i0 + 8];  const float v2 = val[i0 + 8];
        const int   c3 = col[i0 + 12]; const float v3 = val[i0 + 12];
        uint4 u0 = *(const uint4*)(supb + (((size_t)(unsigned)c0) << 8) + fo);
        uint4 u1 = *(const uint4*)(supb + (((size_t)(unsigned)c1) << 8) + fo);
        uint4 u2 = *(const uint4*)(supb + (((size_t)(unsigned)c2) << 8) + fo);
        uint4 u3 = *(const uint4*)(supb + (((size_t)(unsigned)c3) << 8) + fo);
        S1_FENCE(u0) S1_FMA(u0, v0)
        S1_FENCE(u1) S1_FMA(u1, v1)
        S1_FENCE(u2) S1_FMA(u2, v2)
        S1_FENCE(u3) S1_FMA(u3, v3)
    }
    // tail: up to 15 edges as 1-4 guarded groups (all issued before consume)
    const int rem = n - base;
    if (rem > 0) {
        const int elast = e1 - 1;
        uint4 t0, t1, t2, t3;
        float w0 = 0.f, w1 = 0.f, w2 = 0.f, w3 = 0.f;
        {
            int gi = e0 + base + q; if (gi > elast) gi = elast;
            const int c = col[gi]; w0 = (q < rem) ? val[gi] : 0.f;
            t0 = *(const uint4*)(supb + (((size_t)(unsigned)c) << 8) + fo);
        }
        if (rem > 4) {
            int gi = e0 + base + 4 + q; if (gi > elast) gi = elast;
            const int c = col[gi]; w1 = (4 + q < rem) ? val[gi] : 0.f;
            t1 = *(const uint4*)(supb + (((size_t)(unsigned)c) << 8) + fo);
        }
        if (rem > 8) {
            int gi = e0 + base + 8 + q; if (gi > elast) gi = elast;
            const int c = col[gi]; w2 = (8 + q < rem) ? val[gi] : 0.f;
            t2 = *(const uint4*)(supb + (((size_t)(unsigned)c) << 8) + fo);
        }
        if (rem > 12) {
            int gi = e0 + base + 12 + q; if (gi > elast) gi = elast;
            const int c = col[gi]; w3 = (12 + q < rem) ? val[gi] : 0.f;
            t3 = *(const uint4*)(supb + (((size_t)(unsigned)c) << 8) + fo);
        }
        { S1_FENCE(t0) S1_FMA(t0, w0) }
        if (rem > 4)  { S1_FENCE(t1) S1_FMA(t1, w1) }
        if (rem > 8)  { S1_FENCE(t2) S1_FMA(t2, w2) }
        if (rem > 12) { S1_FENCE(t3) S1_FMA(t3, w3) }
    }

    // fold the 4 quarters (f preserved by xor 16/32)
    a0 += __shfl_xor(a0, 16, 64); a1 += __shfl_xor(a1, 16, 64);
    a2 += __shfl_xor(a2, 16, 64); a3 += __shfl_xor(a3, 16, 64);
    a4 += __shfl_xor(a4, 16, 64); a5 += __shfl_xor(a5, 16, 64);
    a6 += __shfl_xor(a6, 16, 64); a7 += __shfl_xor(a7, 16, 64);
    a0 += __shfl_xor(a0, 32, 64); a1 += __shfl_xor(a1, 32, 64);
    a2 += __shfl_xor(a2, 32, 64); a3 += __shfl_xor(a3, 32, 64);
    a4 += __shfl_xor(a4, 32, 64); a5 += __shfl_xor(a5, 32, 64);
    a6 += __shfl_xor(a6, 32, 64); a7 += __shfl_xor(a7, 32, 64);

    if (q == 0) {
        const float4 ba = *(const float4*)(b1 + f * 8);
        const float4 bc = *(const float4*)(b1 + f * 8 + 4);
        const float o0 = fmaxf(a0 + ba.x, 0.f), o1 = fmaxf(a1 + ba.y, 0.f);
        const float o2 = fmaxf(a2 + ba.z, 0.f), o3 = fmaxf(a3 + ba.w, 0.f);
        const float o4 = fmaxf(a4 + bc.x, 0.f), o5 = fmaxf(a5 + bc.y, 0.f);
        const float o6 = fmaxf(a6 + bc.z, 0.f), o7 = fmaxf(a7 + bc.w, 0.f);
        uint4 pk;
        pk.x = (unsigned)f2b(o0) | ((unsigned)f2b(o1) << 16);
        pk.y = (unsigned)f2b(o2) | ((unsigned)f2b(o3) << 16);
        pk.z = (unsigned)f2b(o4) | ((unsigned)f2b(o5) << 16);
        pk.w = (unsigned)f2b(o6) | ((unsigned)f2b(o7) << 16);
        *(uint4*)(h + ((unsigned)wid << 6) + (f << 2)) = pk;
    }
}

// ---- GEMM2 (MFMA): sup2_bf16[N,64(pad)] = bf16( h[N,128] @ W2 ) ------------
// output rows padded to 128 B so spmm2 gathers hit exactly one L2 line.
__global__ __launch_bounds__(256) void k_gemm2(
    const bf16_t* __restrict__ h, const bf16_t* __restrict__ w2t,
    bf16_t* __restrict__ out, int nrows)
{
    __shared__ __align__(16) bf16_t As[128][136];  // [row][k]
    __shared__ __align__(16) bf16_t Bs[48][136];   // [col][k]

    const int tid  = threadIdx.x;
    const int wave = tid >> 6, lane = tid & 63;
    const int lm = lane & 15, quad = lane >> 4;
    const int r0 = blockIdx.x * 128;

    {
        const int row = tid >> 1, half = tid & 1;
        const int gr = r0 + row;
        uint4* dst = (uint4*)&As[row][half * 64];
        if (gr < nrows) {
            const uint4* src = (const uint4*)(h + (size_t)gr * GCN_NHID + half * 64);
#pragma unroll
            for (int i = 0; i < 8; i++) dst[i] = src[i];
        } else {
#pragma unroll
            for (int i = 0; i < 8; i++) dst[i] = make_uint4(0,0,0,0);
        }
    }
    // stage B: 48 rows x 16 uint4 (full 256 B row)
    for (int idx = tid; idx < 48 * 16; idx += 256) {
        const int c = idx >> 4, seg = idx & 15;
        ((uint4*)&Bs[c][0])[seg] = ((const uint4*)(w2t + (size_t)c * GCN_NHID))[seg];
    }
    __syncthreads();

    f32x4 acc[2][3] = {};
#pragma unroll
    for (int ks = 0; ks < 4; ks++) {
        bf16x8 af[2], bfr[3];
#pragma unroll
        for (int i = 0; i < 2; i++)
            af[i] = *(const bf16x8*)&As[wave*32 + i*16 + lm][ks*32 + quad*8];
#pragma unroll
        for (int j = 0; j < 3; j++)
            bfr[j] = *(const bf16x8*)&Bs[j*16 + lm][ks*32 + quad*8];
#pragma unroll
        for (int i = 0; i < 2; i++)
#pragma unroll
            for (int j = 0; j < 3; j++)
                acc[i][j] = __builtin_amdgcn_mfma_f32_16x16x32_bf16(
                    af[i], bfr[j], acc[i][j], 0, 0, 0);
    }

#pragma unroll
    for (int i = 0; i < 2; i++) {
#pragma unroll
        for (int reg = 0; reg < 4; reg++) {
            const int gr = r0 + wave*32 + i*16 + quad*4 + reg;
            if (gr < nrows) {
#pragma unroll
                for (int j = 0; j < 3; j++) {
                    const int gc = j*16 + lm;          // 0..47, cols 40+ are pad
                    out[(size_t)gr * SUP2_LD + gc] = (bf16_t)acc[i][j][reg];
                }
                // zero pad cols 48..63 (keeps spmm2 gathers garbage-free)
                out[(size_t)gr * SUP2_LD + 48 + lm] = (bf16_t)0.f;
            }
        }
    }
}

// ---- spmm2 + bias + log_softmax -> out[N,40] fp32 --------------------------
// wave per row, quarter-gather with dwordx2: quarter q handles edge 4k+q,
// lane f owns classes 4f..4f+3 (one dwordx2 of the 128 B padded row).
#define S2_FENCE(U) asm volatile("" : "+v"(U.x), "+v"(U.y));
#define S2_FMA(U, V)                                   \
    a0 = fmaf(V, blo(U.x), a0); a1 = fmaf(V, bhi(U.x), a1); \
    a2 = fmaf(V, blo(U.y), a2); a3 = fmaf(V, bhi(U.y), a3);

__global__ __launch_bounds__(256) void k_spmm2_lsm(
    const int* __restrict__ row_ptr, const int* __restrict__ col,
    const float* __restrict__ val, const bf16_t* __restrict__ sup2,
    const float* __restrict__ b2, float* __restrict__ out, int nrows)
{
    const int wid  = (blockIdx.x * blockDim.x + threadIdx.x) >> 6;
    const int lane = threadIdx.x & 63;
    if (wid >= nrows) return;
    const int q = lane >> 4;
    const int f = lane & 15;            // classes 4f..4f+3 (valid for f<10)
    const int e0 = __builtin_amdgcn_readfirstlane(row_ptr[wid]);
    const int e1 = __builtin_amdgcn_readfirstlane(row_ptr[wid + 1]);
    const int n  = e1 - e0;
    const char* supb = (const char*)sup2;
    const int fo = f * 8;               // byte offset within 128 B row

    float a0=0.f,a1=0.f,a2=0.f,a3=0.f;

    int base = 0;
    for (; base + 16 <= n; base += 16) {
        const int i0 = e0 + base + q;
        const int   c0 = col[i0];      const float v0 = val[i0];
        const int   c1 = col[i0 + 4];  const float v1 = val[i0 + 4];
        const int   c2 = col[i0 + 8];  const float v2 = val[i0 + 8];
        const int   c3 = col[i0 + 12]; const float v3 = val[i0 + 12];
        uint2 u0 = *(const uint2*)(supb + (((size_t)(unsigned)c0) << 7) + fo);
        uint2 u1 = *(const uint2*)(supb + (((size_t)(unsigned)c1) << 7) + fo);
        uint2 u2 = *(const uint2*)(supb + (((size_t)(unsigned)c2) << 7) + fo);
        uint2 u3 = *(const uint2*)(supb + (((size_t)(unsigned)c3) << 7) + fo);
        S2_FENCE(u0) S2_FMA(u0, v0)
        S2_FENCE(u1) S2_FMA(u1, v1)
        S2_FENCE(u2) S2_FMA(u2, v2)
        S2_FENCE(u3) S2_FMA(u3, v3)
    }
    const int rem = n - base;
    if (rem > 0) {
        const int elast = e1 - 1;
        uint2 t0, t1, t2, t3;
        float w0 = 0.f, w1 = 0.f, w2 = 0.f, w3 = 0.f;
        {
            int gi = e0 + base + q; if (gi > elast) gi = elast;
            const int c = col[gi]; w0 = (q < rem) ? val[gi] : 0.f;
            t0 = *(const uint2*)(supb + (((size_t)(unsigned)c) << 7) + fo);
        }
        if (rem > 4) {
            int gi = e0 + base + 4 + q; if (gi > elast) gi = elast;
            const int c = col[gi]; w1 = (4 + q < rem) ? val[gi] : 0.f;
            t1 = *(const uint2*)(supb + (((size_t)(unsigned)c) << 7) + fo);
        }
        if (rem > 8) {
            int gi = e0 + base + 8 + q; if (gi > elast) gi = elast;
            const int c = col[gi]; w2 = (8 + q < rem) ? val[gi] : 0.f;
            t2 = *(const uint2*)(supb + (((size_t)(unsigned)c) << 7) + fo);
        }
        if (rem > 12) {
            int gi = e0 + base + 12 + q; if (gi > elast) gi = elast;
            const int c = col[gi]; w3 = (12 + q < rem) ? val[gi] : 0.f;
            t3 = *(const uint2*)(supb + (((size_t)(unsigned)c) << 7) + fo);
        }
        { S2_FENCE(t0) S2_FMA(t0, w0) }
        if (rem > 4)  { S2_FENCE(t1) S2_FMA(t1, w1) }
        if (rem > 8)  { S2_FENCE(t2) S2_FMA(t2, w2) }
        if (rem > 12) { S2_FENCE(t3) S2_FMA(t3, w3) }
    }

    // fold quarters
    a0 += __shfl_xor(a0, 16, 64); a1 += __shfl_xor(a1, 16, 64);
    a2 += __shfl_xor(a2, 16, 64); a3 += __shfl_xor(a3, 16, 64);
    a0 += __shfl_xor(a0, 32, 64); a1 += __shfl_xor(a1, 32, 64);
    a2 += __shfl_xor(a2, 32, 64); a3 += __shfl_xor(a3, 32, 64);

    // bias + log_softmax across the 16-lane f dimension (classes 4f..4f+3)
    const bool av = (f < 10);
    float l0 = -INFINITY, l1 = -INFINITY, l2 = -INFINITY, l3 = -INFINITY;
    if (av) {
        const float4 bb = *(const float4*)(b2 + f * 4);
        l0 = a0 + bb.x; l1 = a1 + bb.y; l2 = a2 + bb.z; l3 = a3 + bb.w;
    }
    float m = fmaxf(fmaxf(l0, l1), fmaxf(l2, l3));
    m = fmaxf(m, __shfl_xor(m, 1, 64));
    m = fmaxf(m, __shfl_xor(m, 2, 64));
    m = fmaxf(m, __shfl_xor(m, 4, 64));
    m = fmaxf(m, __shfl_xor(m, 8, 64));
    float s = av ? (__expf(l0 - m) + __expf(l1 - m) + __expf(l2 - m) + __expf(l3 - m)) : 0.f;
    s += __shfl_xor(s, 1, 64);
    s += __shfl_xor(s, 2, 64);
    s += __shfl_xor(s, 4, 64);
    s += __shfl_xor(s, 8, 64);

    if (av && q == 0) {
        const float lse = m + __logf(s);
        float4 o; o.x = l0 - lse; o.y = l1 - lse; o.z = l2 - lse; o.w = l3 - lse;
        *(float4*)(out + (size_t)wid * GCN_NCLASS + f * 4) = o;
    }
}

// ---------------------------------------------------------------------------
extern "C" void kernel_launch(void* const* d_in, const int* in_sizes, int n_in,
                              void* d_out, int out_size, void* d_ws, size_t ws_size,
                              hipStream_t stream)
{
    const float* x       = (const float*)d_in[0];
    const int*   adj_row = (const int*)  d_in[1];
    const int*   adj_col = (const int*)  d_in[2];
    const float* adj_val = (const float*)d_in[3];
    // d_in[4] = i (unused)
    const float* W1 = (const float*)d_in[5];
    const float* b1 = (const float*)d_in[6];
    const float* W2 = (const float*)d_in[7];
    const float* b2 = (const float*)d_in[8];
    float* out = (float*)d_out;

    const int N = in_sizes[0] / GCN_NFEAT;   // 100000
    const int E = in_sizes[1];               // 3200000

    // workspace layout (1 KiB aligned chunks)
    char* ws = (char*)d_ws;
    size_t off = 0;
    int* row_ptr = (int*)(ws + off);
    off += (((size_t)(N + 1) * sizeof(int)) + 1023) & ~(size_t)1023;
    bf16_t* w1t = (bf16_t*)(ws + off);                 // 128*256 bf16
    off += ((size_t)GCN_NHID * GCN_NFEAT * 2 + 1023) & ~(size_t)1023;
    bf16_t* w2t = (bf16_t*)(ws + off);                 // 48*128 bf16
    off += ((size_t)48 * GCN_NHID * 2 + 1023) & ~(size_t)1023;
    bf16_t* sup1 = (bf16_t*)(ws + off);                // N*128 bf16
    off += ((size_t)N * GCN_NHID * 2 + 1023) & ~(size_t)1023;
    bf16_t* h = (bf16_t*)(ws + off);                   // N*128 bf16
    bf16_t* sup2 = sup1;                               // reuse sup1 (N*64 bf16 padded)

    k_row_ptr<<<(N + 1 + 255) / 256, 256, 0, stream>>>(adj_row, row_ptr, N, E);
    k_prep_w1t<<<GCN_NHID * GCN_NFEAT / 256, 256, 0, stream>>>(W1, w1t);
    k_prep_w2t<<<(48 * GCN_NHID + 255) / 256, 256, 0, stream>>>(W2, w2t);
    k_gemm1<<<(N + 127) / 128, 256, 0, stream>>>(x, w1t, sup1, N);
    k_spmm1<<<(N + 3) / 4, 256, 0, stream>>>(row_ptr, adj_col, adj_val,
                                             sup1, b1, (unsigned int*)h, N);
    k_gemm2<<<(N + 127) / 128, 256, 0, stream>>>(h, w2t, sup2, N);
    k_spmm2_lsm<<<(N + 3) / 4, 256, 0, stream>>>(row_ptr, adj_col, adj_val,
                                                 sup2, b2, out, N);
}